// Round 1
// baseline (77.344 us; speedup 1.0000x reference)
//
#include <hip/hip_runtime.h>
#include <math.h>

// Problem sizes (fixed by reference)
constexpr int B    = 512;
constexpr int NIN  = 1024;
constexpr int NK   = 128;
constexpr int DK   = 5;
constexpr int NF   = NK * DK;     // 640 flattened kernel columns, n = k*5+d
constexpr int NOUT = NIN + NK;    // 1152 output row width

// ---------------------------------------------------------------------------
// Kernel 1: s[n] = exp(lws[n]) / ||theta[:, n]||_2     (n = k*5+d, 640 cols)
// grid: 10 blocks x 256 threads; block handles 64 columns, 4-way row split
// ---------------------------------------------------------------------------
__global__ __launch_bounds__(256) void scale_kernel(
        const float* __restrict__ theta,   // [1024][640]
        const float* __restrict__ lws,     // [640]
        float* __restrict__ s) {           // [640]
    __shared__ float red[4][64];
    const int t  = threadIdx.x;
    const int c  = t & 63;
    const int p  = t >> 6;
    const int n  = blockIdx.x * 64 + c;
    float sum = 0.f;
    #pragma unroll 4
    for (int m = 0; m < NIN / 4; ++m) {
        float v = theta[(p + 4 * m) * NF + n];
        sum += v * v;
    }
    red[p][c] = sum;
    __syncthreads();
    if (p == 0) {
        float tot = red[0][c] + red[1][c] + red[2][c] + red[3][c];
        s[n] = __expf(lws[n]) * rsqrtf(tot);
    }
}

// ---------------------------------------------------------------------------
// Kernel 2: actvT[n][b] = s[n] * sum_i theta[i][n] * x[b][i]
// Classic LDS-tiled GEMM, tile 64(n) x 64(b), BK=32, 4x4 micro-tile.
// grid: (640/64, 512/64) = (10, 8); 256 threads.
// ---------------------------------------------------------------------------
__global__ __launch_bounds__(256) void gemm_kernel(
        const float* __restrict__ x,       // [512][1024]
        const float* __restrict__ theta,   // [1024][640]
        const float* __restrict__ s,       // [640]
        float* __restrict__ actvT) {       // [640][512]
    // pad 68: row stride 272B, 16B-aligned so float4 LDS reads stay b128
    __shared__ float Wl[32][68];
    __shared__ float Xl[32][68];

    const int t  = threadIdx.x;
    const int n0 = blockIdx.x * 64;
    const int b0 = blockIdx.y * 64;
    const int tb = t & 15;   // b minor -> coalesced epilogue stores
    const int tn = t >> 4;

    float acc[4][4] = {};

    for (int i0 = 0; i0 < NIN; i0 += 32) {
        __syncthreads();
        // stage W tile [32 i][64 n]
        {
            const int r = t >> 4, c = (t & 15) * 4;
            const float4 w0 = *(const float4*)&theta[(i0 + r) * NF + n0 + c];
            const float4 w1 = *(const float4*)&theta[(i0 + r + 16) * NF + n0 + c];
            *(float4*)&Wl[r][c]      = w0;
            *(float4*)&Wl[r + 16][c] = w1;
        }
        // stage X tile transposed: Xl[i][b]
        {
            const int bl = t >> 2, cc = (t & 3) * 8;
            const float4 xa = *(const float4*)&x[(b0 + bl) * NIN + i0 + cc];
            const float4 xb = *(const float4*)&x[(b0 + bl) * NIN + i0 + cc + 4];
            Xl[cc + 0][bl] = xa.x; Xl[cc + 1][bl] = xa.y;
            Xl[cc + 2][bl] = xa.z; Xl[cc + 3][bl] = xa.w;
            Xl[cc + 4][bl] = xb.x; Xl[cc + 5][bl] = xb.y;
            Xl[cc + 6][bl] = xb.z; Xl[cc + 7][bl] = xb.w;
        }
        __syncthreads();
        #pragma unroll
        for (int kk = 0; kk < 32; ++kk) {
            const float4 wv = *(const float4*)&Wl[kk][tn * 4];
            const float4 xv = *(const float4*)&Xl[kk][tb * 4];
            acc[0][0] += wv.x * xv.x; acc[0][1] += wv.x * xv.y;
            acc[0][2] += wv.x * xv.z; acc[0][3] += wv.x * xv.w;
            acc[1][0] += wv.y * xv.x; acc[1][1] += wv.y * xv.y;
            acc[1][2] += wv.y * xv.z; acc[1][3] += wv.y * xv.w;
            acc[2][0] += wv.z * xv.x; acc[2][1] += wv.z * xv.y;
            acc[2][2] += wv.z * xv.z; acc[2][3] += wv.z * xv.w;
            acc[3][0] += wv.w * xv.x; acc[3][1] += wv.w * xv.y;
            acc[3][2] += wv.w * xv.z; acc[3][3] += wv.w * xv.w;
        }
    }

    // epilogue: scale by s[n], float4 store per n-row
    #pragma unroll
    for (int j = 0; j < 4; ++j) {
        const int n = n0 + tn * 4 + j;
        const float sc = s[n];
        float4 v;
        v.x = acc[j][0] * sc; v.y = acc[j][1] * sc;
        v.z = acc[j][2] * sc; v.w = acc[j][3] * sc;
        *(float4*)&actvT[n * B + b0 + tb * 4] = v;
    }
}

// ---------------------------------------------------------------------------
// Kernel 3: f[b,k] = sum_{b' != b} exp(-sum_d |a[b,k,d]-a[b',k,d]|) + bias[k]
// grid: (128 k, 4 b-quarters); 256 threads = 128 b-rows x 2 b'-halves.
// actvT rows 5k..5k+4 are one contiguous 2560-float slab -> flat LDS copy.
// ---------------------------------------------------------------------------
__global__ __launch_bounds__(256) void pairwise_kernel(
        const float* __restrict__ actvT,   // [640][512]
        const float* __restrict__ bias,    // [128]
        float* __restrict__ out) {         // [512][1152]
    __shared__ float a[DK * B];            // [5][512]
    __shared__ float red[256];

    const int k = blockIdx.x;
    const int q = blockIdx.y;
    const int t = threadIdx.x;

    const float* src = &actvT[k * DK * B];
    #pragma unroll
    for (int j = 0; j < (DK * B) / 256; ++j)
        a[t + 256 * j] = src[t + 256 * j];
    __syncthreads();

    const int bl = t & 127;
    const int h  = t >> 7;               // wave-uniform
    const int b  = q * 128 + bl;

    const float a0 = a[0 * B + b];
    const float a1 = a[1 * B + b];
    const float a2 = a[2 * B + b];
    const float a3 = a[3 * B + b];
    const float a4 = a[4 * B + b];

    float acc = 0.f;
    const int bp0 = h * 256;
    #pragma unroll 4
    for (int m = 0; m < 256; ++m) {
        const int bp = bp0 + m;          // wave-uniform -> LDS broadcast reads
        float dist = fabsf(a0 - a[0 * B + bp]);
        dist += fabsf(a1 - a[1 * B + bp]);
        dist += fabsf(a2 - a[2 * B + bp]);
        dist += fabsf(a3 - a[3 * B + bp]);
        dist += fabsf(a4 - a[4 * B + bp]);
        const float w = __expf(-dist);
        acc += (bp == b) ? 0.f : w;      // diagonal: exp(-(d+1e6)) == 0
    }
    red[t] = acc;
    __syncthreads();
    if (t < 128) {
        const float f = red[t] + red[t + 128] + bias[k];
        out[(q * 128 + t) * NOUT + NIN + k] = f;
    }
}

// ---------------------------------------------------------------------------
// Kernel 4: out[b][0:1024] = x[b][:]   (float4 passthrough)
// grid 512 x 256: one float4 per thread
// ---------------------------------------------------------------------------
__global__ __launch_bounds__(256) void copyx_kernel(
        const float* __restrict__ x, float* __restrict__ out) {
    const int id = blockIdx.x * 256 + threadIdx.x;   // 0 .. 131071
    const int b  = id >> 8;                          // /256 float4 per row
    const int c4 = id & 255;
    const float4 v = ((const float4*)x)[id];
    ((float4*)out)[b * (NOUT / 4) + c4] = v;
}

// ---------------------------------------------------------------------------
extern "C" void kernel_launch(void* const* d_in, const int* in_sizes, int n_in,
                              void* d_out, int out_size, void* d_ws, size_t ws_size,
                              hipStream_t stream) {
    const float* x     = (const float*)d_in[0];   // [512,1024]
    const float* theta = (const float*)d_in[1];   // [1024,128,5]
    const float* lws   = (const float*)d_in[2];   // [128,5]
    const float* bias  = (const float*)d_in[3];   // [128]
    float* out = (float*)d_out;                   // [512,1152]

    float* s     = (float*)d_ws;                  // 640 floats (pad to 1024)
    float* actvT = s + 1024;                      // 640*512 floats

    scale_kernel<<<dim3(NF / 64), 256, 0, stream>>>(theta, lws, s);
    gemm_kernel<<<dim3(NF / 64, B / 64), 256, 0, stream>>>(x, theta, s, actvT);
    pairwise_kernel<<<dim3(NK, 4), 256, 0, stream>>>(actvT, bias, out);
    copyx_kernel<<<dim3((B * NIN / 4) / 256), 256, 0, stream>>>(x, out);
}

// Round 2
// 49.858 us; speedup vs baseline: 1.5513x; 1.5513x over previous
//
#include <hip/hip_runtime.h>
#include <math.h>

// Problem sizes (fixed by reference)
constexpr int B    = 512;
constexpr int NIN  = 1024;
constexpr int NK   = 128;
constexpr int DK   = 5;
constexpr int NF   = NK * DK;     // 640 flattened kernel columns, n = k*5+d
constexpr int NOUT = NIN + NK;    // 1152 output row width

// ---------------------------------------------------------------------------
// Kernel 1a: ps[g][n] = sum over 64 rows (g-th chunk) of theta[:,n]^2
// grid (10, 16) x 256 threads
// ---------------------------------------------------------------------------
__global__ __launch_bounds__(256) void scale_partial(
        const float* __restrict__ theta,   // [1024][640]
        float* __restrict__ ps) {          // [16][640]
    __shared__ float red[4][64];
    const int t  = threadIdx.x;
    const int c  = t & 63;
    const int p  = t >> 6;
    const int n  = blockIdx.x * 64 + c;
    const int r0 = blockIdx.y * 64;
    float sum = 0.f;
    #pragma unroll
    for (int m = 0; m < 16; ++m) {
        const float v = theta[(r0 + p + 4 * m) * NF + n];
        sum += v * v;
    }
    red[p][c] = sum;
    __syncthreads();
    if (p == 0)
        ps[blockIdx.y * NF + n] = red[0][c] + red[1][c] + red[2][c] + red[3][c];
}

// ---------------------------------------------------------------------------
// Kernel 1b: s[n] = exp(lws[n]) * rsqrt(sum_g ps[g][n])   (1 block, 640 thr)
// ---------------------------------------------------------------------------
__global__ __launch_bounds__(640) void scale_finish(
        const float* __restrict__ ps,      // [16][640]
        const float* __restrict__ lws,     // [640]
        float* __restrict__ s) {           // [640]
    const int n = threadIdx.x;
    float sum = 0.f;
    #pragma unroll
    for (int g = 0; g < 16; ++g) sum += ps[g * NF + n];
    s[n] = __expf(lws[n]) * rsqrtf(sum);
}

// ---------------------------------------------------------------------------
// Kernel 2: split-K GEMM.  actvP[z][n][b] = sum_{i in chunk z} theta[i][n]*x[b][i]
// tile 64(n) x 64(b), BK=32, 4x4 micro-tile; grid (10, 8, SPLIT), 256 thr.
// ---------------------------------------------------------------------------
template <int SPLIT>
__global__ __launch_bounds__(256) void gemm_kernel(
        const float* __restrict__ x,       // [512][1024]
        const float* __restrict__ theta,   // [1024][640]
        float* __restrict__ actvP) {       // [SPLIT][640][512]
    __shared__ float Wl[32][68];
    __shared__ float Xl[32][68];

    const int t  = threadIdx.x;
    const int n0 = blockIdx.x * 64;
    const int b0 = blockIdx.y * 64;
    const int z  = blockIdx.z;
    const int tb = t & 15;
    const int tn = t >> 4;
    constexpr int KC = NIN / SPLIT;

    float acc[4][4] = {};

    for (int i0 = z * KC; i0 < (z + 1) * KC; i0 += 32) {
        __syncthreads();
        {   // stage W tile [32 i][64 n]
            const int r = t >> 4, c = (t & 15) * 4;
            const float4 w0 = *(const float4*)&theta[(i0 + r) * NF + n0 + c];
            const float4 w1 = *(const float4*)&theta[(i0 + r + 16) * NF + n0 + c];
            *(float4*)&Wl[r][c]      = w0;
            *(float4*)&Wl[r + 16][c] = w1;
        }
        {   // stage X tile transposed: Xl[i][b]
            const int bl = t >> 2, cc = (t & 3) * 8;
            const float4 xa = *(const float4*)&x[(b0 + bl) * NIN + i0 + cc];
            const float4 xb = *(const float4*)&x[(b0 + bl) * NIN + i0 + cc + 4];
            Xl[cc + 0][bl] = xa.x; Xl[cc + 1][bl] = xa.y;
            Xl[cc + 2][bl] = xa.z; Xl[cc + 3][bl] = xa.w;
            Xl[cc + 4][bl] = xb.x; Xl[cc + 5][bl] = xb.y;
            Xl[cc + 6][bl] = xb.z; Xl[cc + 7][bl] = xb.w;
        }
        __syncthreads();
        #pragma unroll
        for (int kk = 0; kk < 32; ++kk) {
            const float4 wv = *(const float4*)&Wl[kk][tn * 4];
            const float4 xv = *(const float4*)&Xl[kk][tb * 4];
            acc[0][0] += wv.x * xv.x; acc[0][1] += wv.x * xv.y;
            acc[0][2] += wv.x * xv.z; acc[0][3] += wv.x * xv.w;
            acc[1][0] += wv.y * xv.x; acc[1][1] += wv.y * xv.y;
            acc[1][2] += wv.y * xv.z; acc[1][3] += wv.y * xv.w;
            acc[2][0] += wv.z * xv.x; acc[2][1] += wv.z * xv.y;
            acc[2][2] += wv.z * xv.z; acc[2][3] += wv.z * xv.w;
            acc[3][0] += wv.w * xv.x; acc[3][1] += wv.w * xv.y;
            acc[3][2] += wv.w * xv.z; acc[3][3] += wv.w * xv.w;
        }
    }

    float* dst = actvP + (size_t)z * NF * B;
    #pragma unroll
    for (int j = 0; j < 4; ++j) {
        const int n = n0 + tn * 4 + j;
        float4 v;
        v.x = acc[j][0]; v.y = acc[j][1]; v.z = acc[j][2]; v.w = acc[j][3];
        *(float4*)&dst[n * B + b0 + tb * 4] = v;
    }
}

// ---------------------------------------------------------------------------
// Kernel 3: f[b,k] = sum_{b'} exp(-sum_d |a[b,k,d]-a[b',k,d]|) - 1 + bias[k]
// (diagonal term is exp(0)=1 exactly -> subtract 1 instead of masking)
// Stages the split-K reduction + s[] scaling while filling LDS.
// grid (128 k, 4 b-quarters); 256 threads = 128 b x 2 b'-halves.
// ---------------------------------------------------------------------------
template <int SPLIT>
__global__ __launch_bounds__(256) void pairwise_kernel(
        const float* __restrict__ actvP,   // [SPLIT][640][512]
        const float* __restrict__ s,       // [640]
        const float* __restrict__ bias,    // [128]
        float* __restrict__ out) {         // [512][1152]
    __shared__ float a[DK * B];            // [5][512]
    __shared__ float red[256];

    const int k = blockIdx.x;
    const int q = blockIdx.y;
    const int t = threadIdx.x;

    const float* base = &actvP[(size_t)k * DK * B];
    #pragma unroll
    for (int j = 0; j < (DK * B) / 256; ++j) {
        const int idx = t + 256 * j;
        float sum = 0.f;
        #pragma unroll
        for (int z = 0; z < SPLIT; ++z) sum += base[(size_t)z * NF * B + idx];
        a[idx] = sum * s[k * DK + (idx >> 9)];   // (idx>>9) block-uniform per j
    }
    __syncthreads();

    const int bl = t & 127;
    const int h  = t >> 7;               // wave-uniform
    const int b  = q * 128 + bl;

    const float a0 = a[0 * B + b];
    const float a1 = a[1 * B + b];
    const float a2 = a[2 * B + b];
    const float a3 = a[3 * B + b];
    const float a4 = a[4 * B + b];

    union F4 { float4 v; float f[4]; };

    float acc = 0.f;
    const int bp0 = h * 256;
    #pragma unroll 2
    for (int m = 0; m < 64; ++m) {
        const int bp = bp0 + 4 * m;      // wave-uniform -> LDS broadcast b128
        F4 v0, v1, v2, v3, v4;
        v0.v = *(const float4*)&a[0 * B + bp];
        v1.v = *(const float4*)&a[1 * B + bp];
        v2.v = *(const float4*)&a[2 * B + bp];
        v3.v = *(const float4*)&a[3 * B + bp];
        v4.v = *(const float4*)&a[4 * B + bp];
        #pragma unroll
        for (int u = 0; u < 4; ++u) {
            const float d0 = a0 - v0.f[u];
            const float d1 = a1 - v1.f[u];
            const float d2 = a2 - v2.f[u];
            const float d3 = a3 - v3.f[u];
            const float d4 = a4 - v4.f[u];
            const float dist = ((fabsf(d0) + fabsf(d1)) + (fabsf(d2) + fabsf(d3)))
                               + fabsf(d4);
            acc += __expf(-dist);
        }
    }
    red[t] = acc;
    __syncthreads();
    if (t < 128) {
        const float f = red[t] + red[t + 128] - 1.0f + bias[k];
        out[(q * 128 + t) * NOUT + NIN + k] = f;
    }
}

// ---------------------------------------------------------------------------
// Kernel 4: out[b][0:1024] = x[b][:]   (float4 passthrough)
// ---------------------------------------------------------------------------
__global__ __launch_bounds__(256) void copyx_kernel(
        const float* __restrict__ x, float* __restrict__ out) {
    const int id = blockIdx.x * 256 + threadIdx.x;
    const int b  = id >> 8;
    const int c4 = id & 255;
    const float4 v = ((const float4*)x)[id];
    ((float4*)out)[b * (NOUT / 4) + c4] = v;
}

// ---------------------------------------------------------------------------
template <int SPLIT>
static void launch_all(const float* x, const float* theta, const float* lws,
                       const float* bias, float* out, float* ps, float* s,
                       float* actvP, hipStream_t stream) {
    scale_partial<<<dim3(NF / 64, 16), 256, 0, stream>>>(theta, ps);
    scale_finish<<<dim3(1), 640, 0, stream>>>(ps, lws, s);
    gemm_kernel<SPLIT><<<dim3(NF / 64, B / 64, SPLIT), 256, 0, stream>>>(x, theta, actvP);
    pairwise_kernel<SPLIT><<<dim3(NK, 4), 256, 0, stream>>>(actvP, s, bias, out);
    copyx_kernel<<<dim3((B * NIN / 4) / 256), 256, 0, stream>>>(x, out);
}

extern "C" void kernel_launch(void* const* d_in, const int* in_sizes, int n_in,
                              void* d_out, int out_size, void* d_ws, size_t ws_size,
                              hipStream_t stream) {
    const float* x     = (const float*)d_in[0];   // [512,1024]
    const float* theta = (const float*)d_in[1];   // [1024,128,5]
    const float* lws   = (const float*)d_in[2];   // [128,5]
    const float* bias  = (const float*)d_in[3];   // [128]
    float* out = (float*)d_out;                   // [512,1152]

    float* ps    = (float*)d_ws;                  // 16*640 floats
    float* s     = ps + 16 * NF;                  // 640 floats
    float* actvP = ps + 16384;                    // SPLIT*640*512 floats (aligned)

    const size_t head = 16384u * 4u;
    const size_t slab = (size_t)NF * B * 4u;

    if (ws_size >= head + 8 * slab)
        launch_all<8>(x, theta, lws, bias, out, ps, s, actvP, stream);
    else if (ws_size >= head + 4 * slab)
        launch_all<4>(x, theta, lws, bias, out, ps, s, actvP, stream);
    else if (ws_size >= head + 2 * slab)
        launch_all<2>(x, theta, lws, bias, out, ps, s, actvP, stream);
    else
        launch_all<1>(x, theta, lws, bias, out, ps, s, actvP, stream);
}

// Round 3
// 40.223 us; speedup vs baseline: 1.9229x; 1.2395x over previous
//
#include <hip/hip_runtime.h>
#include <math.h>

// Problem sizes (fixed by reference)
constexpr int B    = 512;
constexpr int NIN  = 1024;
constexpr int NK   = 128;
constexpr int DK   = 5;
constexpr int NF   = NK * DK;     // 640 flattened kernel columns, n = k*5+d
constexpr int NOUT = NIN + NK;    // 1152 output row width
#define LOG2E 1.44269504088896f

// ---------------------------------------------------------------------------
// Kernel 1: split-K GEMM + fused theta^2 partial sums.
//   actvP[z][n][b] = sum_{i in chunk z} theta[i][n] * x[b][i]
//   ps[z][n]       = sum_{i in chunk z} theta[i][n]^2      (from y==0 blocks)
// tile 64(n) x 64(b), BK=32, 4x4 micro-tile; grid (10, 8, SPLIT), 256 thr.
// ---------------------------------------------------------------------------
template <int SPLIT>
__global__ __launch_bounds__(256) void gemm_kernel(
        const float* __restrict__ x,       // [512][1024]
        const float* __restrict__ theta,   // [1024][640]
        float* __restrict__ actvP,         // [SPLIT][640][512]
        float* __restrict__ ps) {          // [SPLIT][640]
    __shared__ float Wl[32][68];
    __shared__ float Xl[32][68];

    const int t  = threadIdx.x;
    const int n0 = blockIdx.x * 64;
    const int b0 = blockIdx.y * 64;
    const int z  = blockIdx.z;
    const int tb = t & 15;
    const int tn = t >> 4;
    constexpr int KC = NIN / SPLIT;
    const bool do_ps = (blockIdx.y == 0);

    float acc[4][4] = {};
    float sq[4] = {0.f, 0.f, 0.f, 0.f};

    for (int i0 = z * KC; i0 < (z + 1) * KC; i0 += 32) {
        __syncthreads();
        {   // stage W tile [32 i][64 n]; fold theta^2 partials from regs
            const int r = t >> 4, c = (t & 15) * 4;
            const float4 w0 = *(const float4*)&theta[(i0 + r) * NF + n0 + c];
            const float4 w1 = *(const float4*)&theta[(i0 + r + 16) * NF + n0 + c];
            *(float4*)&Wl[r][c]      = w0;
            *(float4*)&Wl[r + 16][c] = w1;
            if (do_ps) {
                sq[0] += w0.x * w0.x + w1.x * w1.x;
                sq[1] += w0.y * w0.y + w1.y * w1.y;
                sq[2] += w0.z * w0.z + w1.z * w1.z;
                sq[3] += w0.w * w0.w + w1.w * w1.w;
            }
        }
        {   // stage X tile transposed: Xl[i][b]
            const int bl = t >> 2, cc = (t & 3) * 8;
            const float4 xa = *(const float4*)&x[(b0 + bl) * NIN + i0 + cc];
            const float4 xb = *(const float4*)&x[(b0 + bl) * NIN + i0 + cc + 4];
            Xl[cc + 0][bl] = xa.x; Xl[cc + 1][bl] = xa.y;
            Xl[cc + 2][bl] = xa.z; Xl[cc + 3][bl] = xa.w;
            Xl[cc + 4][bl] = xb.x; Xl[cc + 5][bl] = xb.y;
            Xl[cc + 6][bl] = xb.z; Xl[cc + 7][bl] = xb.w;
        }
        __syncthreads();
        #pragma unroll
        for (int kk = 0; kk < 32; ++kk) {
            const float4 wv = *(const float4*)&Wl[kk][tn * 4];
            const float4 xv = *(const float4*)&Xl[kk][tb * 4];
            acc[0][0] += wv.x * xv.x; acc[0][1] += wv.x * xv.y;
            acc[0][2] += wv.x * xv.z; acc[0][3] += wv.x * xv.w;
            acc[1][0] += wv.y * xv.x; acc[1][1] += wv.y * xv.y;
            acc[1][2] += wv.y * xv.z; acc[1][3] += wv.y * xv.w;
            acc[2][0] += wv.z * xv.x; acc[2][1] += wv.z * xv.y;
            acc[2][2] += wv.z * xv.z; acc[2][3] += wv.z * xv.w;
            acc[3][0] += wv.w * xv.x; acc[3][1] += wv.w * xv.y;
            acc[3][2] += wv.w * xv.z; acc[3][3] += wv.w * xv.w;
        }
    }

    // store partial actv tile
    float* dst = actvP + (size_t)z * NF * B;
    #pragma unroll
    for (int j = 0; j < 4; ++j) {
        const int n = n0 + tn * 4 + j;
        float4 v;
        v.x = acc[j][0]; v.y = acc[j][1]; v.z = acc[j][2]; v.w = acc[j][3];
        *(float4*)&dst[n * B + b0 + tb * 4] = v;
    }

    // reduce + store theta^2 partials (reuse Wl after a barrier)
    if (do_ps) {
        __syncthreads();
        {
            const int r = t >> 4, c = (t & 15) * 4;
            Wl[r][c + 0] = sq[0]; Wl[r][c + 1] = sq[1];
            Wl[r][c + 2] = sq[2]; Wl[r][c + 3] = sq[3];
        }
        __syncthreads();
        if (t < 64) {
            float tot = 0.f;
            #pragma unroll
            for (int rr = 0; rr < 16; ++rr) tot += Wl[rr][t];
            ps[z * NF + n0 + t] = tot;
        }
    }
}

// ---------------------------------------------------------------------------
// Kernel 2: fused finish:
//   s[n]   = exp(lws[n]) * rsqrt(sum_z ps[z][n]) * log2(e)
//   a[d,b] = (sum_z actvP[z][k*5+d][b]) * s
//   f[b,k] = sum_{b'} exp2(-sum_d |a[d,b]-a[d,b']|) - 1 + bias[k]
//   plus x passthrough: block (k,q) copies x row k*4+q.
// grid (128 k, 4 b-quarters); 256 threads; each thread owns 2 b-rows and one
// wave-uniform quarter of b' (g = t>>6).
// ---------------------------------------------------------------------------
template <int SPLIT>
__global__ __launch_bounds__(256) void pairwise_kernel(
        const float* __restrict__ actvP,   // [SPLIT][640][512]
        const float* __restrict__ ps,      // [SPLIT][640]
        const float* __restrict__ lws,     // [640]
        const float* __restrict__ bias,    // [128]
        const float* __restrict__ x,       // [512][1024]
        float* __restrict__ out) {         // [512][1152]
    __shared__ float a[DK * B];            // [5][512]
    __shared__ float red[4 * 128];
    __shared__ float s_sh[DK];
    __shared__ float red_ps[5 * SPLIT];

    const int k = blockIdx.x;
    const int q = blockIdx.y;
    const int t = threadIdx.x;

    // fused x passthrough: one row per block
    {
        const int row = k * 4 + q;
        const float4 v = ((const float4*)x)[row * (NIN / 4) + t];
        ((float4*)out)[row * (NOUT / 4) + t] = v;
    }

    // scale inputs (overlaps with the big actvP staging below)
    if (t < 5 * SPLIT)
        red_ps[t] = ps[(t / 5) * NF + k * DK + (t % 5)];

    // split-K reduction into registers
    float regs[10];
    const float* base = actvP + (size_t)k * DK * B;
    #pragma unroll
    for (int j = 0; j < 10; ++j) {
        const int idx = t + 256 * j;
        float sum = 0.f;
        #pragma unroll
        for (int z = 0; z < SPLIT; ++z) sum += base[(size_t)z * NF * B + idx];
        regs[j] = sum;
    }
    __syncthreads();
    if (t < DK) {
        float sum = 0.f;
        #pragma unroll
        for (int z = 0; z < SPLIT; ++z) sum += red_ps[z * 5 + t];
        s_sh[t] = __expf(lws[k * DK + t]) * rsqrtf(sum) * LOG2E;
    }
    __syncthreads();
    #pragma unroll
    for (int j = 0; j < 10; ++j)
        a[t + 256 * j] = regs[j] * s_sh[j >> 1];   // j>>1 compile-time per unroll
    __syncthreads();

    const int g  = t >> 6;               // wave-uniform b' quarter
    const int r  = t & 63;
    const int ba = q * 128 + r;
    const int bb = ba + 64;

    const float A0 = a[0 * B + ba], A1 = a[1 * B + ba], A2 = a[2 * B + ba],
                A3 = a[3 * B + ba], A4 = a[4 * B + ba];
    const float B0 = a[0 * B + bb], B1 = a[1 * B + bb], B2 = a[2 * B + bb],
                B3 = a[3 * B + bb], B4 = a[4 * B + bb];

    union F4 { float4 v; float f[4]; };

    float accA = 0.f, accB = 0.f;
    const int bp0 = g * 128;
    #pragma unroll 2
    for (int m = 0; m < 32; ++m) {
        const int bp = bp0 + 4 * m;      // wave-uniform -> LDS broadcast b128
        F4 v0, v1, v2, v3, v4;
        v0.v = *(const float4*)&a[0 * B + bp];
        v1.v = *(const float4*)&a[1 * B + bp];
        v2.v = *(const float4*)&a[2 * B + bp];
        v3.v = *(const float4*)&a[3 * B + bp];
        v4.v = *(const float4*)&a[4 * B + bp];
        #pragma unroll
        for (int u = 0; u < 4; ++u) {
            const float dA = ((fabsf(A0 - v0.f[u]) + fabsf(A1 - v1.f[u]))
                            + (fabsf(A2 - v2.f[u]) + fabsf(A3 - v3.f[u])))
                            + fabsf(A4 - v4.f[u]);
            accA += __builtin_amdgcn_exp2f(-dA);
            const float dB = ((fabsf(B0 - v0.f[u]) + fabsf(B1 - v1.f[u]))
                            + (fabsf(B2 - v2.f[u]) + fabsf(B3 - v3.f[u])))
                            + fabsf(B4 - v4.f[u]);
            accB += __builtin_amdgcn_exp2f(-dB);
        }
    }
    red[g * 128 + r]      = accA;
    red[g * 128 + 64 + r] = accB;
    __syncthreads();
    if (t < 128) {
        const float f = ((red[0 * 128 + t] + red[1 * 128 + t])
                       + (red[2 * 128 + t] + red[3 * 128 + t]))
                       - 1.0f + bias[k];
        out[(q * 128 + t) * NOUT + NIN + k] = f;
    }
}

// ---------------------------------------------------------------------------
template <int SPLIT>
static void launch_all(const float* x, const float* theta, const float* lws,
                       const float* bias, float* out, float* ps,
                       float* actvP, hipStream_t stream) {
    gemm_kernel<SPLIT><<<dim3(NF / 64, B / 64, SPLIT), 256, 0, stream>>>(
        x, theta, actvP, ps);
    pairwise_kernel<SPLIT><<<dim3(NK, 4), 256, 0, stream>>>(
        actvP, ps, lws, bias, x, out);
}

extern "C" void kernel_launch(void* const* d_in, const int* in_sizes, int n_in,
                              void* d_out, int out_size, void* d_ws, size_t ws_size,
                              hipStream_t stream) {
    const float* x     = (const float*)d_in[0];   // [512,1024]
    const float* theta = (const float*)d_in[1];   // [1024,128,5]
    const float* lws   = (const float*)d_in[2];   // [128,5]
    const float* bias  = (const float*)d_in[3];   // [128]
    float* out = (float*)d_out;                   // [512,1152]

    float* ps    = (float*)d_ws;                  // SPLIT*640 floats
    float* actvP = ps + 16384;                    // SPLIT*640*512 floats

    const size_t head = 16384u * 4u;
    const size_t slab = (size_t)NF * B * 4u;

    if (ws_size >= head + 8 * slab)
        launch_all<8>(x, theta, lws, bias, out, ps, actvP, stream);
    else if (ws_size >= head + 4 * slab)
        launch_all<4>(x, theta, lws, bias, out, ps, actvP, stream);
    else if (ws_size >= head + 2 * slab)
        launch_all<2>(x, theta, lws, bias, out, ps, actvP, stream);
    else
        launch_all<1>(x, theta, lws, bias, out, ps, actvP, stream);
}

// Round 4
// 39.146 us; speedup vs baseline: 1.9758x; 1.0275x over previous
//
#include <hip/hip_runtime.h>
#include <math.h>

constexpr int B    = 512;
constexpr int NIN  = 1024;
constexpr int NK   = 128;
constexpr int DK   = 5;
constexpr int NF   = NK * DK;     // 640 flattened kernel columns, n = k*5+d
constexpr int NOUT = NIN + NK;    // 1152 output row width
constexpr int SPLITK = 4;         // K chunks in MFMA gemm
constexpr int PSCH   = 16;        // theta^2 partial chunks (64 rows each)
#define LOG2E 1.44269504088896f

typedef _Float16 f16x8 __attribute__((ext_vector_type(8)));
typedef _Float16 f16x4 __attribute__((ext_vector_type(4)));
typedef float    f32x4 __attribute__((ext_vector_type(4)));

// ---------------------------------------------------------------------------
// Kernel 1 (prep), grid 224:
//  blocks 0..159 : transpose+convert theta[1024][640] f32 -> thetaT[640][1024]
//                  fp16 (64i x 64n tiles) and write theta^2 partials ps[16][640]
//  blocks 160..223: convert x[512][1024] f32 -> xH fp16 (row-major unchanged)
// ---------------------------------------------------------------------------
__global__ __launch_bounds__(256) void prep_kernel(
        const float* __restrict__ theta,   // [1024][640]
        const float* __restrict__ x,       // [512][1024]
        _Float16* __restrict__ thetaT,     // [640][1024]
        _Float16* __restrict__ xH,         // [512][1024]
        float* __restrict__ ps) {          // [16][640]
    const int t = threadIdx.x;
    if (blockIdx.x < 160) {
        __shared__ _Float16 Th[64][72];    // [n][i], pad 72 halves
        __shared__ float    red[16][64];
        const int ti = blockIdx.x / 10;    // i-tile (0..15)
        const int ni = blockIdx.x % 10;    // n-tile (0..9)
        const int i0 = ti * 64, n0 = ni * 64;
        const int sr = t >> 4;             // 4-row group (0..15)
        const int c4 = (t & 15) * 4;       // 4-col group

        // read 4x4 f32 sub-tile, accumulate theta^2, transpose to LDS halves
        float4 v0 = *(const float4*)&theta[(i0 + sr * 4 + 0) * NF + n0 + c4];
        float4 v1 = *(const float4*)&theta[(i0 + sr * 4 + 1) * NF + n0 + c4];
        float4 v2 = *(const float4*)&theta[(i0 + sr * 4 + 2) * NF + n0 + c4];
        float4 v3 = *(const float4*)&theta[(i0 + sr * 4 + 3) * NF + n0 + c4];
        red[sr][c4 + 0] = v0.x * v0.x + v1.x * v1.x + v2.x * v2.x + v3.x * v3.x;
        red[sr][c4 + 1] = v0.y * v0.y + v1.y * v1.y + v2.y * v2.y + v3.y * v3.y;
        red[sr][c4 + 2] = v0.z * v0.z + v1.z * v1.z + v2.z * v2.z + v3.z * v3.z;
        red[sr][c4 + 3] = v0.w * v0.w + v1.w * v1.w + v2.w * v2.w + v3.w * v3.w;
        f16x4 h;
        h[0]=(_Float16)v0.x; h[1]=(_Float16)v1.x; h[2]=(_Float16)v2.x; h[3]=(_Float16)v3.x;
        *(f16x4*)&Th[c4 + 0][sr * 4] = h;
        h[0]=(_Float16)v0.y; h[1]=(_Float16)v1.y; h[2]=(_Float16)v2.y; h[3]=(_Float16)v3.y;
        *(f16x4*)&Th[c4 + 1][sr * 4] = h;
        h[0]=(_Float16)v0.z; h[1]=(_Float16)v1.z; h[2]=(_Float16)v2.z; h[3]=(_Float16)v3.z;
        *(f16x4*)&Th[c4 + 2][sr * 4] = h;
        h[0]=(_Float16)v0.w; h[1]=(_Float16)v1.w; h[2]=(_Float16)v2.w; h[3]=(_Float16)v3.w;
        *(f16x4*)&Th[c4 + 3][sr * 4] = h;
        __syncthreads();

        // contiguous fp16 row writes: thread t -> row n=t>>2, two 8-half chunks
        const int n  = t >> 2;
        const int cg = t & 3;
        #pragma unroll
        for (int it = 0; it < 2; ++it) {
            const int i8 = cg * 8 + it * 32;
            f16x8 hv = *(const f16x8*)&Th[n][i8];
            *(f16x8*)&thetaT[(size_t)(n0 + n) * NIN + i0 + i8] = hv;
        }
        // theta^2 partial: column sums over the 64 rows of this i-tile
        if (t < 64) {
            float tot = 0.f;
            #pragma unroll
            for (int rr = 0; rr < 16; ++rr) tot += red[rr][t];
            ps[ti * NF + n0 + t] = tot;
        }
    } else {
        const int bx = blockIdx.x - 160;   // 0..63
        const float4* xin = (const float4*)x;
        #pragma unroll
        for (int j = 0; j < 4; ++j) {
            const int idx2 = bx * 1024 + j * 256 + t;
            const float4 va = xin[2 * idx2];
            const float4 vb = xin[2 * idx2 + 1];
            f16x8 hv;
            hv[0]=(_Float16)va.x; hv[1]=(_Float16)va.y;
            hv[2]=(_Float16)va.z; hv[3]=(_Float16)va.w;
            hv[4]=(_Float16)vb.x; hv[5]=(_Float16)vb.y;
            hv[6]=(_Float16)vb.z; hv[7]=(_Float16)vb.w;
            *((f16x8*)xH + idx2) = hv;
        }
    }
}

// ---------------------------------------------------------------------------
// Kernel 2: MFMA fp16 GEMM, no LDS, no barriers.
//   actvP[z][n][b] = sum_{k in chunk z} thetaT[n][k] * xH[b][k]
// Each wave owns one 16(n) x 16(b) tile, K-chunk 256 (8 MFMAs).
// A-frag (theta): row n = lane&15, k = (lane>>4)*8 + j  (k-contiguous 16B)
// B-frag (x):     col b = lane&15, k = (lane>>4)*8 + j  (k-contiguous 16B)
// C:              col b = lane&15, row n = (lane>>4)*4 + reg   [m89/m91]
// grid (8 b-groups, 40 n-tiles, 4 z) x 256 threads (4 waves = 4 b-tiles).
// ---------------------------------------------------------------------------
__global__ __launch_bounds__(256) void mfma_gemm(
        const _Float16* __restrict__ thetaT,  // [640][1024]
        const _Float16* __restrict__ xH,      // [512][1024]
        float* __restrict__ actvP) {          // [SPLITK][640][512]
    const int t   = threadIdx.x;
    const int w   = t >> 6;
    const int l   = t & 63;
    const int r16 = l & 15;
    const int kg  = l >> 4;

    const int bt = blockIdx.x * 4 + w;        // 0..31
    const int b0 = bt * 16;
    const int n0 = blockIdx.y * 16;
    const int z  = blockIdx.z;
    const int k0 = z * (NIN / SPLITK);        // 256-chunk

    const _Float16* ap = thetaT + (size_t)(n0 + r16) * NIN + k0 + kg * 8;
    const _Float16* bp = xH     + (size_t)(b0 + r16) * NIN + k0 + kg * 8;

    f32x4 acc = {0.f, 0.f, 0.f, 0.f};
    #pragma unroll
    for (int kk = 0; kk < (NIN / SPLITK) / 32; ++kk) {
        const f16x8 av = *(const f16x8*)(ap + kk * 32);
        const f16x8 bv = *(const f16x8*)(bp + kk * 32);
        acc = __builtin_amdgcn_mfma_f32_16x16x32_f16(av, bv, acc, 0, 0, 0);
    }

    float* dst = actvP + (size_t)z * NF * B + (size_t)(n0 + kg * 4) * B + b0 + r16;
    dst[0 * B] = acc[0];
    dst[1 * B] = acc[1];
    dst[2 * B] = acc[2];
    dst[3 * B] = acc[3];
}

// ---------------------------------------------------------------------------
// Kernel 3: fused finish (same inner loop as R3):
//   s[d] = exp(lws) * rsqrt(sum_c ps[c]) * log2e;  a = (sum_z actvP)*s
//   f[b,k] = sum_{b'} exp2(-sum_d |a-a'|) - 1 + bias[k];  + x passthrough.
// grid (128 k, 4 b-quarters) x 256 threads.
// ---------------------------------------------------------------------------
__global__ __launch_bounds__(256) void pairwise_kernel(
        const float* __restrict__ actvP,   // [SPLITK][640][512]
        const float* __restrict__ ps,      // [16][640]
        const float* __restrict__ lws,     // [640]
        const float* __restrict__ bias,    // [128]
        const float* __restrict__ x,       // [512][1024]
        float* __restrict__ out) {         // [512][1152]
    __shared__ float a[DK * B];            // [5][512]
    __shared__ float red[4 * 128];
    __shared__ float s_sh[DK];
    __shared__ float red_ps[5 * PSCH];

    const int k = blockIdx.x;
    const int q = blockIdx.y;
    const int t = threadIdx.x;

    // fused x passthrough: one row per block
    {
        const int row = k * 4 + q;
        const float4 v = ((const float4*)x)[row * (NIN / 4) + t];
        ((float4*)out)[row * (NOUT / 4) + t] = v;
    }

    if (t < 5 * PSCH)
        red_ps[t] = ps[(t / 5) * NF + k * DK + (t % 5)];

    // split-K reduction into registers
    float regs[10];
    const float* base = actvP + (size_t)k * DK * B;
    #pragma unroll
    for (int j = 0; j < 10; ++j) {
        const int idx = t + 256 * j;
        float sum = 0.f;
        #pragma unroll
        for (int z = 0; z < SPLITK; ++z) sum += base[(size_t)z * NF * B + idx];
        regs[j] = sum;
    }
    __syncthreads();
    if (t < DK) {
        float sum = 0.f;
        #pragma unroll
        for (int c = 0; c < PSCH; ++c) sum += red_ps[c * 5 + t];
        s_sh[t] = __expf(lws[k * DK + t]) * rsqrtf(sum) * LOG2E;
    }
    __syncthreads();
    #pragma unroll
    for (int j = 0; j < 10; ++j)
        a[t + 256 * j] = regs[j] * s_sh[j >> 1];
    __syncthreads();

    const int g  = t >> 6;               // wave-uniform b' quarter
    const int r  = t & 63;
    const int ba = q * 128 + r;
    const int bb = ba + 64;

    const float A0 = a[0 * B + ba], A1 = a[1 * B + ba], A2 = a[2 * B + ba],
                A3 = a[3 * B + ba], A4 = a[4 * B + ba];
    const float B0 = a[0 * B + bb], B1 = a[1 * B + bb], B2 = a[2 * B + bb],
                B3 = a[3 * B + bb], B4 = a[4 * B + bb];

    union F4 { float4 v; float f[4]; };

    float accA = 0.f, accB = 0.f;
    const int bp0 = g * 128;
    #pragma unroll 2
    for (int m = 0; m < 32; ++m) {
        const int bp = bp0 + 4 * m;      // wave-uniform -> LDS broadcast b128
        F4 v0, v1, v2, v3, v4;
        v0.v = *(const float4*)&a[0 * B + bp];
        v1.v = *(const float4*)&a[1 * B + bp];
        v2.v = *(const float4*)&a[2 * B + bp];
        v3.v = *(const float4*)&a[3 * B + bp];
        v4.v = *(const float4*)&a[4 * B + bp];
        #pragma unroll
        for (int u = 0; u < 4; ++u) {
            const float dA = ((fabsf(A0 - v0.f[u]) + fabsf(A1 - v1.f[u]))
                            + (fabsf(A2 - v2.f[u]) + fabsf(A3 - v3.f[u])))
                            + fabsf(A4 - v4.f[u]);
            accA += __builtin_amdgcn_exp2f(-dA);
            const float dB = ((fabsf(B0 - v0.f[u]) + fabsf(B1 - v1.f[u]))
                            + (fabsf(B2 - v2.f[u]) + fabsf(B3 - v3.f[u])))
                            + fabsf(B4 - v4.f[u]);
            accB += __builtin_amdgcn_exp2f(-dB);
        }
    }
    red[g * 128 + r]      = accA;
    red[g * 128 + 64 + r] = accB;
    __syncthreads();
    if (t < 128) {
        const float f = ((red[0 * 128 + t] + red[1 * 128 + t])
                       + (red[2 * 128 + t] + red[3 * 128 + t]))
                       - 1.0f + bias[k];
        out[(q * 128 + t) * NOUT + NIN + k] = f;
    }
}

// ---------------------------------------------------------------------------
extern "C" void kernel_launch(void* const* d_in, const int* in_sizes, int n_in,
                              void* d_out, int out_size, void* d_ws, size_t ws_size,
                              hipStream_t stream) {
    const float* x     = (const float*)d_in[0];   // [512,1024]
    const float* theta = (const float*)d_in[1];   // [1024,128,5]
    const float* lws   = (const float*)d_in[2];   // [128,5]
    const float* bias  = (const float*)d_in[3];   // [128]
    float* out = (float*)d_out;                   // [512,1152]

    // ws layout (bytes): ps @0 (40KB), thetaT @64KB (1.25MB),
    // xH @1344KB (1MB), actvP @2432KB (4 x 1.25MB)
    char* wsb = (char*)d_ws;
    float*     ps     = (float*)wsb;
    _Float16*  thetaT = (_Float16*)(wsb + (64 << 10));
    _Float16*  xH     = (_Float16*)(wsb + (1344 << 10));
    float*     actvP  = (float*)(wsb + (2432 << 10));

    prep_kernel<<<dim3(224), 256, 0, stream>>>(theta, x, thetaT, xH, ps);
    mfma_gemm<<<dim3(8, 40, SPLITK), 256, 0, stream>>>(thetaT, xH, actvP);
    pairwise_kernel<<<dim3(NK, 4), 256, 0, stream>>>(actvP, ps, lws, bias, x, out);
}